// Round 1
// baseline (172.473 us; speedup 1.0000x reference)
//
#include <hip/hip_runtime.h>

#define H 4
#define Nq 4096
#define SEG 4
#define LOG2E 1.44269504088896340736f

typedef unsigned short ushortT;
typedef __attribute__((ext_vector_type(8))) short short8;
typedef __attribute__((ext_vector_type(4))) float floatx4;

// round-half-up f32 -> bf16 (inputs are finite, non-NaN here)
static __device__ __forceinline__ ushortT f2bf(float x) {
    unsigned int u = __builtin_bit_cast(unsigned int, x);
    return (ushortT)((u + 0x8000u) >> 16);
}

// ---------------------------------------------------------------------------
// Kernel 1: QKV projection + stack + vec-activation.
//   mat = blockIdx.z: 0 -> Q (activated, pre-scaled by log2e), 1 -> K (activated),
//   2 -> V (raw, stored TRANSPOSED [h][64][N] for the PV B-operand staging).
//   Q,K stored [h][n][64] bf16. All weight reads are block-uniform -> s_load.
// ---------------------------------------------------------------------------
__global__ __launch_bounds__(256) void qkv_kernel(
    const float* __restrict__ ax, const float* __restrict__ vx,
    const float* __restrict__ Waq, const float* __restrict__ Wvq,
    const float* __restrict__ Wak, const float* __restrict__ Wvk,
    const float* __restrict__ Wav, const float* __restrict__ Wvv,
    ushortT* __restrict__ Qg, ushortT* __restrict__ Kg, ushortT* __restrict__ Vtg)
{
    const int h   = blockIdx.y;
    const int mat = blockIdx.z;
    const int n   = blockIdx.x * 256 + threadIdx.x;

    const float* Wa = (mat == 0 ? Waq : (mat == 1 ? Wak : Wav)) + h * (16 * 64);
    const float* Wv = (mat == 0 ? Wvq : (mat == 1 ? Wvk : Wvv)) + h * (16 * 16);

    float axr[64];
    {
        const floatx4* p = (const floatx4*)(ax + (size_t)n * 64);
        #pragma unroll
        for (int i = 0; i < 16; i++) {
            floatx4 t = p[i];
            axr[4*i+0] = t.x; axr[4*i+1] = t.y; axr[4*i+2] = t.z; axr[4*i+3] = t.w;
        }
    }
    float vxr[48];
    {
        const floatx4* p = (const floatx4*)(vx + (size_t)n * 48);
        #pragma unroll
        for (int i = 0; i < 12; i++) {
            floatx4 t = p[i];
            vxr[4*i+0] = t.x; vxr[4*i+1] = t.y; vxr[4*i+2] = t.z; vxr[4*i+3] = t.w;
        }
    }

    __attribute__((aligned(16))) ushortT outb[64];
    const float sc_extra = (mat == 0) ? LOG2E : 1.0f;

    #pragma unroll
    for (int c = 0; c < 16; c++) {
        float a = 0.f, v0 = 0.f, v1 = 0.f, v2 = 0.f;
        #pragma unroll
        for (int d = 0; d < 64; d++) a = fmaf(Wa[c*64 + d], axr[d], a);
        #pragma unroll
        for (int j = 0; j < 16; j++) {
            float w = Wv[c*16 + j];
            v0 = fmaf(w, vxr[3*j+0], v0);
            v1 = fmaf(w, vxr[3*j+1], v1);
            v2 = fmaf(w, vxr[3*j+2], v2);
        }
        float s = 1.0f;
        if (mat < 2) {
            float nsq = a*a + v0*v0 + v1*v1 + v2*v2;
            s = rsqrtf(sqrtf(1.0f + nsq)) * sc_extra;   // (1+nsq)^(-1/4)
        }
        outb[4*c+0] = f2bf(a  * s);
        outb[4*c+1] = f2bf(v0 * s);
        outb[4*c+2] = f2bf(v1 * s);
        outb[4*c+3] = f2bf(v2 * s);
    }

    if (mat < 2) {
        ushortT* dst = (mat == 0 ? Qg : Kg) + ((size_t)(h * Nq + n)) * 64;
        #pragma unroll
        for (int i = 0; i < 8; i++) ((short8*)dst)[i] = ((const short8*)outb)[i];
    } else {
        #pragma unroll
        for (int d = 0; d < 64; d++)
            Vtg[((size_t)(h * 64 + d)) * Nq + n] = outb[d];   // coalesced across lanes
    }
}

// ---------------------------------------------------------------------------
// Kernel 2: flash attention core (split-K, no online max -- fp32 range covers it).
//   Block: 256 thr = 4 waves, each wave owns 16 queries. blockIdx = (qtile, h, seg).
//   Per 64-key tile: S = (log2e*Q)@K^T via 2 mfma per 16-key subtile; fp32 bias
//   2c*pq.pk - c|pk|^2 - c|pq|^2 added; p = exp2(.); P->bf16 via per-wave LDS
//   buffer (C-layout write, A-layout read); PV via 8 mfma against transposed V.
//   Emits partial (sum p*V, sum p) per segment.
// ---------------------------------------------------------------------------
__global__ __launch_bounds__(256, 4) void attn_kernel(
    const ushortT* __restrict__ Qg, const ushortT* __restrict__ Kg,
    const ushortT* __restrict__ Vtg,
    const float* __restrict__ pos_q, const float* __restrict__ pos_k,
    float* __restrict__ partO, float* __restrict__ partL)
{
    __shared__ ushortT kE[64 * 72];      // K tile   [key][feat], stride 72 (pad)
    __shared__ ushortT vE[64 * 72];      // V tile   [feat][key], stride 72
    __shared__ floatx4 poskE[64];        // (kx,ky,kz,|pk|^2)
    __shared__ ushortT pE[4][16 * 72];   // per-wave P [qrow][key], stride 72

    const int tid  = threadIdx.x;
    const int w    = tid >> 6;
    const int lane = tid & 63;
    const int quad = lane >> 4;
    const int ln   = lane & 15;
    const int h    = blockIdx.y;
    const int seg  = blockIdx.z;
    const int qw   = blockIdx.x * 64 + w * 16;

    const float c = LOG2E / (float)(1 << (2 * h));   // log2e / r0sq[h]

    // Q A-fragments (feats 0..31 and 32..63); Q already scaled by log2e
    const short8* qp = (const short8*)(Qg + ((size_t)(h * Nq + qw + ln)) * 64 + quad * 8);
    const short8 qf0 = qp[0];
    const short8 qf1 = qp[4];   // +32 elements

    // per-lane row constants (rows quad*4+r)
    float pqsx[4], pqsy[4], pqsz[4], brow[4];
    #pragma unroll
    for (int r = 0; r < 4; r++) {
        const int q = qw + quad * 4 + r;
        const float x = pos_q[(size_t)(h * Nq + q) * 3 + 0];
        const float y = pos_q[(size_t)(h * Nq + q) * 3 + 1];
        const float z = pos_q[(size_t)(h * Nq + q) * 3 + 2];
        pqsx[r] = 2.f * c * x; pqsy[r] = 2.f * c * y; pqsz[r] = 2.f * c * z;
        brow[r] = -c * (x * x + y * y + z * z);   // keep: prevents exp2 overflow
    }

    floatx4 O[4] = {};                       // 16q x 64f accumulator (C-layout x4)
    float lacc[4] = {0.f, 0.f, 0.f, 0.f};
    ushortT* pEw = pE[w];

    const int k0seg = seg * (Nq / SEG);
    for (int kt = 0; kt < (Nq / SEG) / 64; kt++) {
        const int k0 = k0seg + kt * 64;
        __syncthreads();                     // protect LDS reuse from prev tile
        // --- stage K (bf16 [key][64]) and Vt (bf16 [feat][64 keys]) ---
        #pragma unroll
        for (int i = 0; i < 2; i++) {
            const int ch = tid + i * 256;    // 0..511, 16B chunks
            const int row = ch >> 3, part = ch & 7;
            short8 tk = *(const short8*)(Kg + ((size_t)(h * Nq + k0 + row)) * 64 + part * 8);
            *(short8*)&kE[row * 72 + part * 8] = tk;
            short8 tv = *(const short8*)(Vtg + ((size_t)(h * 64 + row)) * Nq + k0 + part * 8);
            *(short8*)&vE[row * 72 + part * 8] = tv;
        }
        if (tid < 64) {
            const float x = pos_k[(size_t)(h * Nq + k0 + tid) * 3 + 0];
            const float y = pos_k[(size_t)(h * Nq + k0 + tid) * 3 + 1];
            const float z = pos_k[(size_t)(h * Nq + k0 + tid) * 3 + 2];
            poskE[tid] = (floatx4){x, y, z, x * x + y * y + z * z};
        }
        __syncthreads();

        // --- S = Q@K^T per 16-key subtile, bias + exp2, P -> per-wave LDS ---
        #pragma unroll
        for (int kk = 0; kk < 4; kk++) {
            const short8 kf0 = *(const short8*)&kE[(kk * 16 + ln) * 72 + quad * 8];
            const short8 kf1 = *(const short8*)&kE[(kk * 16 + ln) * 72 + 32 + quad * 8];
            floatx4 S = {0.f, 0.f, 0.f, 0.f};
            S = __builtin_amdgcn_mfma_f32_16x16x32_bf16(qf0, kf0, S, 0, 0, 0);
            S = __builtin_amdgcn_mfma_f32_16x16x32_bf16(qf1, kf1, S, 0, 0, 0);
            const floatx4 pk4 = poskE[kk * 16 + ln];
            #pragma unroll
            for (int r = 0; r < 4; r++) {
                const float bias = fmaf(-c, pk4.w, brow[r]);
                const float t = fmaf(pqsx[r], pk4.x,
                                fmaf(pqsy[r], pk4.y,
                                fmaf(pqsz[r], pk4.z, bias)));
                const float p = exp2f(S[r] + t);
                lacc[r] += p;
                pEw[(quad * 4 + r) * 72 + kk * 16 + ln] = f2bf(p);
            }
        }
        // --- PV: O += P(16x32) @ V(32x64), two 32-key rounds ---
        #pragma unroll
        for (int r2 = 0; r2 < 2; r2++) {
            const short8 pf = *(const short8*)&pEw[ln * 72 + r2 * 32 + quad * 8];
            #pragma unroll
            for (int g = 0; g < 4; g++) {
                const short8 vf = *(const short8*)&vE[(g * 16 + ln) * 72 + r2 * 32 + quad * 8];
                O[g] = __builtin_amdgcn_mfma_f32_16x16x32_bf16(pf, vf, O[g], 0, 0, 0);
            }
        }
    }

    // row-sum of l across the 16 lanes sharing a quad
    #pragma unroll
    for (int r = 0; r < 4; r++) {
        float v = lacc[r];
        v += __shfl_xor(v, 1, 64);
        v += __shfl_xor(v, 2, 64);
        v += __shfl_xor(v, 4, 64);
        v += __shfl_xor(v, 8, 64);
        lacc[r] = v;
    }

    const int hs = h * SEG + seg;
    #pragma unroll
    for (int r = 0; r < 4; r++) {
        const int q = qw + quad * 4 + r;
        const size_t base = ((size_t)hs * Nq + q) * 64;
        #pragma unroll
        for (int g = 0; g < 4; g++)
            partO[base + g * 16 + ln] = O[g][r];
        if (ln == 0) partL[(size_t)hs * Nq + q] = lacc[r];
    }
}

// ---------------------------------------------------------------------------
// Kernel 3: merge split-K partials, divide by (l * sqrt(N)), and transpose to
//   Of[h][d][n] (so the projection kernel reads coalesced). LDS 64x65 tile.
// ---------------------------------------------------------------------------
__global__ __launch_bounds__(256) void reduce_kernel(
    const float* __restrict__ partO, const float* __restrict__ partL,
    float* __restrict__ Of)
{
    __shared__ float T[64 * 65];
    __shared__ float lsum[64];
    const int tid = threadIdx.x;
    const int q0  = blockIdx.x * 64;
    const int h   = blockIdx.y;

    if (tid < 64) {
        float s = 0.f;
        #pragma unroll
        for (int sg = 0; sg < SEG; sg++)
            s += partL[(size_t)(h * SEG + sg) * Nq + q0 + tid];
        lsum[tid] = s * 64.0f;               // * sqrt(N)
    }
    __syncthreads();

    const int w = tid >> 6, lane = tid & 63;
    #pragma unroll
    for (int k = 0; k < 16; k++) {
        const int q = k * 4 + w;             // wave-uniform
        const int d = lane;                  // coalesced reads
        float acc = 0.f;
        #pragma unroll
        for (int sg = 0; sg < SEG; sg++)
            acc += partO[((size_t)(h * SEG + sg) * Nq + q0 + q) * 64 + d];
        T[d * 65 + q] = acc / lsum[q];
    }
    __syncthreads();
    #pragma unroll
    for (int k = 0; k < 16; k++) {
        const int d = k * 4 + w;
        const int q = lane;                  // coalesced writes
        Of[(size_t)(h * 64 + d) * Nq + q0 + q] = T[d * 65 + q];
    }
}

// ---------------------------------------------------------------------------
// Kernel 4: output projection. Wave-uniform j so W reads scalarize; lane = n so
//   Of reads coalesce. Honors the reference's split: ay = O[0:16],
//   vy[i][v] = O[16+3i+v].
// ---------------------------------------------------------------------------
__global__ __launch_bounds__(256) void proj_kernel(
    const float* __restrict__ Of, const float* __restrict__ Wao,
    const float* __restrict__ Wvo, float* __restrict__ out)
{
    const int tid  = threadIdx.x;
    const int w    = tid >> 6;
    const int lane = tid & 63;
    const int n    = blockIdx.x * 64 + lane;

    float aacc[16] = {};
    float vacc[4][3] = {};

    for (int h = 0; h < 4; h++) {
        float oh[64];
        #pragma unroll
        for (int d = 0; d < 64; d++)
            oh[d] = Of[(size_t)(h * 64 + d) * Nq + n];
        #pragma unroll
        for (int jj = 0; jj < 16; jj++) {
            const int j = w * 16 + jj;
            float acc = aacc[jj];
            #pragma unroll
            for (int i = 0; i < 16; i++)
                acc = fmaf(Wao[(h * 64 + j) * 16 + i], oh[i], acc);
            aacc[jj] = acc;
        }
        #pragma unroll
        for (int jj = 0; jj < 4; jj++) {
            const int j = w * 4 + jj;
            #pragma unroll
            for (int i = 0; i < 16; i++) {
                const float wv = Wvo[(h * 16 + j) * 16 + i];
                vacc[jj][0] = fmaf(wv, oh[16 + 3 * i + 0], vacc[jj][0]);
                vacc[jj][1] = fmaf(wv, oh[16 + 3 * i + 1], vacc[jj][1]);
                vacc[jj][2] = fmaf(wv, oh[16 + 3 * i + 2], vacc[jj][2]);
            }
        }
    }
    #pragma unroll
    for (int jj = 0; jj < 16; jj++)
        out[(size_t)n * 64 + w * 16 + jj] = aacc[jj];
    float* outv = out + (size_t)Nq * 64;
    #pragma unroll
    for (int jj = 0; jj < 4; jj++)
        #pragma unroll
        for (int v = 0; v < 3; v++)
            outv[((size_t)n * 16 + w * 4 + jj) * 3 + v] = vacc[jj][v];
}

// ---------------------------------------------------------------------------
extern "C" void kernel_launch(void* const* d_in, const int* in_sizes, int n_in,
                              void* d_out, int out_size, void* d_ws, size_t ws_size,
                              hipStream_t stream)
{
    const float* ax    = (const float*)d_in[0];
    const float* vx    = (const float*)d_in[1];
    const float* pos_k = (const float*)d_in[2];
    const float* pos_q = (const float*)d_in[3];
    const float* Waq   = (const float*)d_in[4];
    const float* Wvq   = (const float*)d_in[5];
    const float* Wak   = (const float*)d_in[6];
    const float* Wvk   = (const float*)d_in[7];
    const float* Wav   = (const float*)d_in[8];
    const float* Wvv   = (const float*)d_in[9];
    const float* Wao   = (const float*)d_in[10];
    const float* Wvo   = (const float*)d_in[11];
    float* out = (float*)d_out;

    char* ws = (char*)d_ws;
    // layout: Q(2MB) K(2MB) Vt(2MB) partO(16MB) partL(256KB) Of(4MB) = ~26.3MB
    ushortT* Qg  = (ushortT*)(ws);
    ushortT* Kg  = (ushortT*)(ws + (size_t)2 * 1024 * 1024);
    ushortT* Vtg = (ushortT*)(ws + (size_t)4 * 1024 * 1024);
    float* partO = (float*)(ws + (size_t)6 * 1024 * 1024);
    float* partL = (float*)(ws + (size_t)6 * 1024 * 1024 + (size_t)H * SEG * Nq * 64 * 4);
    float* Of    = (float*)((char*)partL + (size_t)H * SEG * Nq * 4);

    qkv_kernel<<<dim3(Nq / 256, H, 3), 256, 0, stream>>>(
        ax, vx, Waq, Wvq, Wak, Wvk, Wav, Wvv, Qg, Kg, Vtg);
    attn_kernel<<<dim3(Nq / 64, H, SEG), 256, 0, stream>>>(
        Qg, Kg, Vtg, pos_q, pos_k, partO, partL);
    reduce_kernel<<<dim3(Nq / 64, H), 256, 0, stream>>>(partO, partL, Of);
    proj_kernel<<<dim3(Nq / 64), 256, 0, stream>>>(Of, Wao, Wvo, out);
}

// Round 2
// 165.954 us; speedup vs baseline: 1.0393x; 1.0393x over previous
//
#include <hip/hip_runtime.h>

#define H 4
#define Nq 4096
#define SEG 4
#define LOG2E 1.44269504088896340736f

typedef unsigned short ushortT;
typedef __attribute__((ext_vector_type(8))) short short8;
typedef __attribute__((ext_vector_type(4))) float floatx4;

// round-half-up f32 -> bf16 (inputs finite)
static __device__ __forceinline__ ushortT f2bf(float x) {
    unsigned int u = __builtin_bit_cast(unsigned int, x);
    return (ushortT)((u + 0x8000u) >> 16);
}

// ---------------------------------------------------------------------------
// Kernel 1: QKV projection + stack + vec-activation.
//   z = mat*2 + chalf; each thread: one n, 8 channels. No big output array ->
//   no spills (v1 spilled: axr+vxr+outb ~190+ VGPR fully unrolled).
//   Weights are block-uniform -> scalar loads.
// ---------------------------------------------------------------------------
__global__ __launch_bounds__(256) void qkv_kernel(
    const float* __restrict__ ax, const float* __restrict__ vx,
    const float* __restrict__ Waq, const float* __restrict__ Wvq,
    const float* __restrict__ Wak, const float* __restrict__ Wvk,
    const float* __restrict__ Wav, const float* __restrict__ Wvv,
    ushortT* __restrict__ Qg, ushortT* __restrict__ Kg, ushortT* __restrict__ Vtg)
{
    const int h     = blockIdx.y;
    const int mat   = blockIdx.z >> 1;
    const int chalf = blockIdx.z & 1;
    const int c0    = chalf * 8;
    const int n     = blockIdx.x * 256 + threadIdx.x;

    const float* Wa = (mat == 0 ? Waq : (mat == 1 ? Wak : Wav)) + h * (16 * 64);
    const float* Wv = (mat == 0 ? Wvq : (mat == 1 ? Wvk : Wvv)) + h * (16 * 16);

    float axr[64];
    {
        const floatx4* p = (const floatx4*)(ax + (size_t)n * 64);
        #pragma unroll
        for (int i = 0; i < 16; i++) {
            floatx4 t = p[i];
            axr[4*i+0] = t.x; axr[4*i+1] = t.y; axr[4*i+2] = t.z; axr[4*i+3] = t.w;
        }
    }
    float vxr[48];
    {
        const floatx4* p = (const floatx4*)(vx + (size_t)n * 48);
        #pragma unroll
        for (int i = 0; i < 12; i++) {
            floatx4 t = p[i];
            vxr[4*i+0] = t.x; vxr[4*i+1] = t.y; vxr[4*i+2] = t.z; vxr[4*i+3] = t.w;
        }
    }

    float acca[8] = {};
    float accv[8][3] = {};
    #pragma unroll
    for (int d = 0; d < 64; d++) {
        #pragma unroll
        for (int cc = 0; cc < 8; cc++)
            acca[cc] = fmaf(Wa[(c0 + cc) * 64 + d], axr[d], acca[cc]);
    }
    #pragma unroll
    for (int j = 0; j < 16; j++) {
        #pragma unroll
        for (int cc = 0; cc < 8; cc++) {
            const float w = Wv[(c0 + cc) * 16 + j];
            accv[cc][0] = fmaf(w, vxr[3*j+0], accv[cc][0]);
            accv[cc][1] = fmaf(w, vxr[3*j+1], accv[cc][1]);
            accv[cc][2] = fmaf(w, vxr[3*j+2], accv[cc][2]);
        }
    }

    const float sc_extra = (mat == 0) ? LOG2E : 1.0f;
    __attribute__((aligned(16))) ushortT ob[32];
    #pragma unroll
    for (int cc = 0; cc < 8; cc++) {
        float a = acca[cc], v0 = accv[cc][0], v1 = accv[cc][1], v2 = accv[cc][2];
        float s = 1.0f;
        if (mat < 2) {
            const float nsq = a*a + v0*v0 + v1*v1 + v2*v2;
            s = rsqrtf(sqrtf(1.0f + nsq)) * sc_extra;   // (1+nsq)^(-1/4)
        }
        ob[4*cc+0] = f2bf(a  * s);
        ob[4*cc+1] = f2bf(v0 * s);
        ob[4*cc+2] = f2bf(v1 * s);
        ob[4*cc+3] = f2bf(v2 * s);
    }

    if (mat < 2) {
        ushortT* dst = (mat == 0 ? Qg : Kg) + ((size_t)(h * Nq + n)) * 64 + c0 * 4;
        #pragma unroll
        for (int i = 0; i < 4; i++) ((short8*)dst)[i] = ((const short8*)ob)[i];
    } else {
        #pragma unroll
        for (int cc = 0; cc < 8; cc++)
            #pragma unroll
            for (int j = 0; j < 4; j++) {
                const int d = c0 * 4 + cc * 4 + j;
                Vtg[((size_t)(h * 64 + d)) * Nq + n] = ob[4*cc+j];  // coalesced
            }
    }
}

// ---------------------------------------------------------------------------
// Kernel 2: flash attention core. Block = 2 waves x 32 queries; K-tile = 64.
//   Each wave's 2 q-groups (16q each) share K/V/pos fragments -> LDS reads per
//   element halved vs v1. P buffer XOR-swizzled (col ^= 16*quad) -> conflict-
//   free ds_write_b16; reads stay contiguous b128 (<=2-way, free).
// ---------------------------------------------------------------------------
__global__ __launch_bounds__(128, 2) void attn_kernel(
    const ushortT* __restrict__ Qg, const ushortT* __restrict__ Kg,
    const ushortT* __restrict__ Vtg,
    const float* __restrict__ pos_q, const float* __restrict__ pos_k,
    float* __restrict__ partO, float* __restrict__ partL)
{
    __shared__ __attribute__((aligned(16))) ushortT kE[64 * 72];  // [key][feat]
    __shared__ __attribute__((aligned(16))) ushortT vE[64 * 72];  // [feat][key]
    __shared__ floatx4 poskE[64];                                 // (x,y,z,|pk|^2)
    __shared__ __attribute__((aligned(16))) ushortT pE[2][32 * 72]; // per-wave P

    const int tid  = threadIdx.x;
    const int w    = tid >> 6;
    const int lane = tid & 63;
    const int quad = lane >> 4;
    const int ln   = lane & 15;
    const int h    = blockIdx.y;
    const int seg  = blockIdx.z;
    const int qw   = blockIdx.x * 64 + w * 32;      // wave's 32 queries

    const float c = LOG2E / (float)(1 << (2 * h)); // log2e / r0sq[h]

    // Q A-fragments for both q-groups (Q pre-scaled by log2e)
    short8 qf[2][2];
    #pragma unroll
    for (int qg = 0; qg < 2; qg++) {
        const short8* qp = (const short8*)(Qg + ((size_t)(h * Nq + qw + qg * 16 + ln)) * 64 + quad * 8);
        qf[qg][0] = qp[0];
        qf[qg][1] = qp[4];
    }

    // per-lane row constants (rows qg*16 + quad*4 + r)
    float pqsx[2][4], pqsy[2][4], pqsz[2][4], brow[2][4];
    #pragma unroll
    for (int qg = 0; qg < 2; qg++)
        #pragma unroll
        for (int r = 0; r < 4; r++) {
            const int q = qw + qg * 16 + quad * 4 + r;
            const float x = pos_q[(size_t)(h * Nq + q) * 3 + 0];
            const float y = pos_q[(size_t)(h * Nq + q) * 3 + 1];
            const float z = pos_q[(size_t)(h * Nq + q) * 3 + 2];
            pqsx[qg][r] = 2.f * c * x; pqsy[qg][r] = 2.f * c * y; pqsz[qg][r] = 2.f * c * z;
            brow[qg][r] = -c * (x * x + y * y + z * z);  // keeps exp2 arg <= ~20
        }

    floatx4 O[2][4] = {};          // [qg][dgroup], C-layout
    float lacc[2][4] = {};

    char* const pEw   = (char*)pE[w];
    const int kvbase  = ln * 144 + quad * 16;           // byte base into kE/vE
    const int pwbase  = quad * 576 + 2 * ln;            // P-write row/col base (bytes)
    const int qswb    = quad * 32;                      // write swizzle (bytes)
    const int lswb    = (ln >> 2) * 32;                 // read swizzle (bytes)
    const int prbase  = ln * 144;                       // P-read row base (bytes)

    const int k0seg = seg * (Nq / SEG);
    for (int kt = 0; kt < (Nq / SEG) / 64; kt++) {
        const int k0 = k0seg + kt * 64;
        __syncthreads();                                // protect LDS reuse
        // --- stage K [key][64f] and Vt [feat][64k]: 1024 16B chunks / 128 thr ---
        #pragma unroll
        for (int i = 0; i < 4; i++) {
            const int ch  = tid + i * 128;              // 0..511
            const int row = ch >> 3, part = ch & 7;
            short8 tk = *(const short8*)(Kg + ((size_t)(h * Nq + k0 + row)) * 64 + part * 8);
            *(short8*)&kE[row * 72 + part * 8] = tk;
            short8 tv = *(const short8*)(Vtg + ((size_t)(h * 64 + row)) * Nq + k0 + part * 8);
            *(short8*)&vE[row * 72 + part * 8] = tv;
        }
        if (tid < 64) {
            const float x = pos_k[(size_t)(h * Nq + k0 + tid) * 3 + 0];
            const float y = pos_k[(size_t)(h * Nq + k0 + tid) * 3 + 1];
            const float z = pos_k[(size_t)(h * Nq + k0 + tid) * 3 + 2];
            poskE[tid] = (floatx4){x, y, z, x * x + y * y + z * z};
        }
        __syncthreads();

        // --- S = Q@K^T; fp32 bias + exp2; P -> swizzled per-wave LDS ---
        #pragma unroll
        for (int kk = 0; kk < 4; kk++) {
            const short8 kf0 = *(const short8*)((char*)kE + kvbase + kk * 2304);
            const short8 kf1 = *(const short8*)((char*)kE + kvbase + kk * 2304 + 64);
            const floatx4 pk4 = poskE[kk * 16 + ln];
            const float px = pk4.x, py = pk4.y, pz = pk4.z;
            const float bcol = -c * pk4.w;
            ushortT* pp = (ushortT*)(pEw + pwbase + (qswb ^ (kk * 32)));
            #pragma unroll
            for (int qg = 0; qg < 2; qg++) {
                floatx4 S = {0.f, 0.f, 0.f, 0.f};
                S = __builtin_amdgcn_mfma_f32_16x16x32_bf16(qf[qg][0], kf0, S, 0, 0, 0);
                S = __builtin_amdgcn_mfma_f32_16x16x32_bf16(qf[qg][1], kf1, S, 0, 0, 0);
                #pragma unroll
                for (int r = 0; r < 4; r++) {
                    const float t = fmaf(pqsx[qg][r], px,
                                    fmaf(pqsy[qg][r], py,
                                    fmaf(pqsz[qg][r], pz, brow[qg][r] + bcol)));
                    const float p = __builtin_amdgcn_exp2f(S[r] + t);
                    lacc[qg][r] += p;
                    pp[qg * 1152 + r * 72] = f2bf(p);
                }
            }
        }
        // --- PV: O[qg] += P(16x32) @ V(32x64); V frags shared across qg ---
        #pragma unroll
        for (int r2 = 0; r2 < 2; r2++) {
            short8 pf[2];
            #pragma unroll
            for (int qg = 0; qg < 2; qg++)
                pf[qg] = *(const short8*)(pEw + prbase + qg * 2304 +
                                          ((r2 * 64 + quad * 16) ^ lswb));
            #pragma unroll
            for (int g = 0; g < 4; g++) {
                const short8 vf = *(const short8*)((char*)vE + kvbase + g * 2304 + r2 * 64);
                O[0][g] = __builtin_amdgcn_mfma_f32_16x16x32_bf16(pf[0], vf, O[0][g], 0, 0, 0);
                O[1][g] = __builtin_amdgcn_mfma_f32_16x16x32_bf16(pf[1], vf, O[1][g], 0, 0, 0);
            }
        }
    }

    // row-sum of l across the 16 lanes sharing a quad
    #pragma unroll
    for (int qg = 0; qg < 2; qg++)
        #pragma unroll
        for (int r = 0; r < 4; r++) {
            float v = lacc[qg][r];
            v += __shfl_xor(v, 1, 64);
            v += __shfl_xor(v, 2, 64);
            v += __shfl_xor(v, 4, 64);
            v += __shfl_xor(v, 8, 64);
            lacc[qg][r] = v;
        }

    const int hs = h * SEG + seg;
    #pragma unroll
    for (int qg = 0; qg < 2; qg++)
        #pragma unroll
        for (int r = 0; r < 4; r++) {
            const int q = qw + qg * 16 + quad * 4 + r;
            const size_t base = ((size_t)hs * Nq + q) * 64;
            #pragma unroll
            for (int g = 0; g < 4; g++)
                partO[base + g * 16 + ln] = O[qg][g][r];
            if (ln == 0) partL[(size_t)hs * Nq + q] = lacc[qg][r];
        }
}

// ---------------------------------------------------------------------------
// Kernel 3: merge split-K partials, divide by (l * sqrt(N)), transpose to
//   Of[h][d][n]. LDS 64x65 tile.
// ---------------------------------------------------------------------------
__global__ __launch_bounds__(256) void reduce_kernel(
    const float* __restrict__ partO, const float* __restrict__ partL,
    float* __restrict__ Of)
{
    __shared__ float T[64 * 65];
    __shared__ float lsum[64];
    const int tid = threadIdx.x;
    const int q0  = blockIdx.x * 64;
    const int h   = blockIdx.y;

    if (tid < 64) {
        float s = 0.f;
        #pragma unroll
        for (int sg = 0; sg < SEG; sg++)
            s += partL[(size_t)(h * SEG + sg) * Nq + q0 + tid];
        lsum[tid] = s * 64.0f;               // * sqrt(N)
    }
    __syncthreads();

    const int w = tid >> 6, lane = tid & 63;
    #pragma unroll
    for (int k = 0; k < 16; k++) {
        const int q = k * 4 + w;
        const int d = lane;
        float acc = 0.f;
        #pragma unroll
        for (int sg = 0; sg < SEG; sg++)
            acc += partO[((size_t)(h * SEG + sg) * Nq + q0 + q) * 64 + d];
        T[d * 65 + q] = acc / lsum[q];
    }
    __syncthreads();
    #pragma unroll
    for (int k = 0; k < 16; k++) {
        const int d = k * 4 + w;
        const int q = lane;
        Of[(size_t)(h * 64 + d) * Nq + q0 + q] = T[d * 65 + q];
    }
}

// ---------------------------------------------------------------------------
// Kernel 4: output projection. ay = O[0:16]; vy[i][v] = O[16+3i+v].
// ---------------------------------------------------------------------------
__global__ __launch_bounds__(256) void proj_kernel(
    const float* __restrict__ Of, const float* __restrict__ Wao,
    const float* __restrict__ Wvo, float* __restrict__ out)
{
    const int tid  = threadIdx.x;
    const int w    = tid >> 6;
    const int lane = tid & 63;
    const int n    = blockIdx.x * 64 + lane;

    float aacc[16] = {};
    float vacc[4][3] = {};

    for (int h = 0; h < 4; h++) {
        float oh[64];
        #pragma unroll
        for (int d = 0; d < 64; d++)
            oh[d] = Of[(size_t)(h * 64 + d) * Nq + n];
        #pragma unroll
        for (int jj = 0; jj < 16; jj++) {
            const int j = w * 16 + jj;
            float acc = aacc[jj];
            #pragma unroll
            for (int i = 0; i < 16; i++)
                acc = fmaf(Wao[(h * 64 + j) * 16 + i], oh[i], acc);
            aacc[jj] = acc;
        }
        #pragma unroll
        for (int jj = 0; jj < 4; jj++) {
            const int j = w * 4 + jj;
            #pragma unroll
            for (int i = 0; i < 16; i++) {
                const float wv = Wvo[(h * 16 + j) * 16 + i];
                vacc[jj][0] = fmaf(wv, oh[16 + 3 * i + 0], vacc[jj][0]);
                vacc[jj][1] = fmaf(wv, oh[16 + 3 * i + 1], vacc[jj][1]);
                vacc[jj][2] = fmaf(wv, oh[16 + 3 * i + 2], vacc[jj][2]);
            }
        }
    }
    #pragma unroll
    for (int jj = 0; jj < 16; jj++)
        out[(size_t)n * 64 + w * 16 + jj] = aacc[jj];
    float* outv = out + (size_t)Nq * 64;
    #pragma unroll
    for (int jj = 0; jj < 4; jj++)
        #pragma unroll
        for (int v = 0; v < 3; v++)
            outv[((size_t)n * 16 + w * 4 + jj) * 3 + v] = vacc[jj][v];
}

// ---------------------------------------------------------------------------
extern "C" void kernel_launch(void* const* d_in, const int* in_sizes, int n_in,
                              void* d_out, int out_size, void* d_ws, size_t ws_size,
                              hipStream_t stream)
{
    const float* ax    = (const float*)d_in[0];
    const float* vx    = (const float*)d_in[1];
    const float* pos_k = (const float*)d_in[2];
    const float* pos_q = (const float*)d_in[3];
    const float* Waq   = (const float*)d_in[4];
    const float* Wvq   = (const float*)d_in[5];
    const float* Wak   = (const float*)d_in[6];
    const float* Wvk   = (const float*)d_in[7];
    const float* Wav   = (const float*)d_in[8];
    const float* Wvv   = (const float*)d_in[9];
    const float* Wao   = (const float*)d_in[10];
    const float* Wvo   = (const float*)d_in[11];
    float* out = (float*)d_out;

    char* ws = (char*)d_ws;
    // layout: Q(2MB) K(2MB) Vt(2MB) partO(16MB) partL(256KB) Of(4MB) = ~26.3MB
    ushortT* Qg  = (ushortT*)(ws);
    ushortT* Kg  = (ushortT*)(ws + (size_t)2 * 1024 * 1024);
    ushortT* Vtg = (ushortT*)(ws + (size_t)4 * 1024 * 1024);
    float* partO = (float*)(ws + (size_t)6 * 1024 * 1024);
    float* partL = (float*)(ws + (size_t)6 * 1024 * 1024 + (size_t)H * SEG * Nq * 64 * 4);
    float* Of    = (float*)((char*)partL + (size_t)H * SEG * Nq * 4);

    qkv_kernel<<<dim3(Nq / 256, H, 6), 256, 0, stream>>>(
        ax, vx, Waq, Wvq, Wak, Wvk, Wav, Wvv, Qg, Kg, Vtg);
    attn_kernel<<<dim3(Nq / 64, H, SEG), 128, 0, stream>>>(
        Qg, Kg, Vtg, pos_q, pos_k, partO, partL);
    reduce_kernel<<<dim3(Nq / 64, H), 256, 0, stream>>>(partO, partL, Of);
    proj_kernel<<<dim3(Nq / 64), 256, 0, stream>>>(Of, Wao, Wvo, out);
}